// Round 3
// baseline (487.840 us; speedup 1.0000x reference)
//
#include <hip/hip_runtime.h>
#include <hip/hip_bf16.h>
#include <cstdint>
#include <cstddef>

#define BB 2
#define SS 2048
#define HH 2048
#define NHH 16
#define DHH 128

using f32x4  = __attribute__((ext_vector_type(4))) float;
using bf16x8 = __attribute__((ext_vector_type(8))) __bf16;
using bf16x4 = __attribute__((ext_vector_type(4))) __bf16;
using bfloat = __bf16;

__device__ inline void gload_lds16(const void* g, void* l) {
    __builtin_amdgcn_global_load_lds(
        (const __attribute__((address_space(1))) void*)g,
        (__attribute__((address_space(3))) void*)l, 16, 0, 0);
}

__device__ inline f32x4 mfma16(bf16x8 a, bf16x8 b, f32x4 c) {
    return __builtin_amdgcn_mfma_f32_16x16x32_bf16(a, b, c, 0, 0, 0);
}

template <int CTRL>
__device__ inline float dpp_max_step(float x) {
    int y = __builtin_amdgcn_update_dpp(0, __builtin_bit_cast(int, x), CTRL, 0xf, 0xf, false);
    return fmaxf(x, __builtin_bit_cast(float, y));
}
// max over the 16-lane row group (lanes lr=0..15 within each lg group)
__device__ inline float rowmax16(float x) {
    x = dpp_max_step<0x121>(x);   // row_ror:1
    x = dpp_max_step<0x122>(x);   // row_ror:2
    x = dpp_max_step<0x124>(x);   // row_ror:4
    x = dpp_max_step<0x128>(x);   // row_ror:8
    return x;
}

// ---------------- fp32 -> bf16 conversion ----------------
__global__ void cvt_bf16(const float* __restrict__ in, bfloat* __restrict__ out, int n4) {
    int i = blockIdx.x * blockDim.x + threadIdx.x;
    if (i >= n4) return;
    float4 v = reinterpret_cast<const float4*>(in)[i];
    bf16x4 o;
    o[0] = (bfloat)v.x; o[1] = (bfloat)v.y; o[2] = (bfloat)v.z; o[3] = (bfloat)v.w;
    reinterpret_cast<bf16x4*>(out)[i] = o;
}

// ---------------- RoPE tables (S x 64) ----------------
__global__ void rope_table(float* __restrict__ cosT, float* __restrict__ sinT) {
    int i = blockIdx.x * blockDim.x + threadIdx.x;
    if (i >= SS * 64) return;
    int s = i >> 6, j = i & 63;
    float invf = powf(10000.0f, -(float)j / 64.0f);
    float ang = (float)s * invf;
    cosT[i] = cosf(ang);
    sinT[i] = sinf(ang);
}

// ---------------- GEMM: C(MxN) = A(MxK) * Bt(NxK)^T + bias ----------------
// OUTMODE: 0 = bf16 row-major, 1 = f32 row-major, 2 = bf16 V-transposed (b,h,d,s)
//          3 = bf16 row-major + RoPE + 1/sqrt(DH) scale (Q), 4 = bf16 + RoPE (K)
template <int OUTMODE>
__global__ __launch_bounds__(256, 2)
void gemm_bt(const bfloat* __restrict__ A, const bfloat* __restrict__ Bt,
             const float* __restrict__ bias, void* __restrict__ C,
             int M, int N, int K,
             const float* __restrict__ cosT, const float* __restrict__ sinT) {
    constexpr int BM = 128, BN = 128, BK = 32;
    __shared__ bfloat As[BM * BK];
    __shared__ bfloat Bs[BN * BK];
    const int t = threadIdx.x, w = t >> 6, l = t & 63;
    const int lr = l & 15, lg = l >> 4;
    const int m0 = blockIdx.x * BM, n0 = blockIdx.y * BN;
    const int wm = (w >> 1) * 64;
    const int base = (t & ~63) * 8;   // wave-uniform LDS element base

    f32x4 acc[4][4] = {};

    for (int kb = 0; kb < K; kb += BK) {
#pragma unroll
        for (int i = 0; i < 2; i++) {
            int idx = i * 256 + t;
            int r = idx >> 2, k8 = (idx & 3) << 3;
            gload_lds16(A  + (size_t)(m0 + r) * K + kb + k8, As + (i * 2048 + base));
            gload_lds16(Bt + (size_t)(n0 + r) * K + kb + k8, Bs + (i * 2048 + base));
        }
        __syncthreads();
        bf16x8 af[4], bfr[4];
#pragma unroll
        for (int mi = 0; mi < 4; mi++)
            af[mi] = *reinterpret_cast<const bf16x8*>(&As[(wm + mi * 16 + lr) * BK + lg * 8]);
#pragma unroll
        for (int ni = 0; ni < 4; ni++) {
            int cb = (w & 1) * 32 + (ni & 1) * 16 + (ni >> 1) * 64;
            bfr[ni] = *reinterpret_cast<const bf16x8*>(&Bs[(cb + lr) * BK + lg * 8]);
        }
#pragma unroll
        for (int mi = 0; mi < 4; mi++)
#pragma unroll
            for (int ni = 0; ni < 4; ni++)
                acc[mi][ni] = mfma16(af[mi], bfr[ni], acc[mi][ni]);
        __syncthreads();
    }

    if (OUTMODE <= 2) {
#pragma unroll
        for (int mi = 0; mi < 4; mi++) {
            int row = m0 + wm + mi * 16 + lg * 4;
#pragma unroll
            for (int ni = 0; ni < 4; ni++) {
                int cb = (w & 1) * 32 + (ni & 1) * 16 + (ni >> 1) * 64;
                int col = n0 + cb + lr;
                float bv = bias[col];
#pragma unroll
                for (int j = 0; j < 4; j++) {
                    float v = acc[mi][ni][j] + bv;
                    if (OUTMODE == 1) {
                        ((float*)C)[(size_t)(row + j) * N + col] = v;
                    } else if (OUTMODE == 0) {
                        ((bfloat*)C)[(size_t)(row + j) * N + col] = (bfloat)v;
                    } else {
                        int bb = (row + j) >> 11;
                        int s  = (row + j) & (SS - 1);
                        ((bfloat*)C)[((size_t)(bb * HH + col)) * SS + s] = (bfloat)v;
                    }
                }
            }
        }
    } else {
        const float qscale = 0.088388347648318447f;   // 1/sqrt(128)
#pragma unroll
        for (int mi = 0; mi < 4; mi++) {
            int row = m0 + wm + mi * 16 + lg * 4;
#pragma unroll
            for (int ni = 0; ni < 2; ni++) {
                int d = (w & 1) * 32 + ni * 16 + lr;      // 0..63 within head
                int col1 = n0 + d, col2 = col1 + 64;
                float b1 = bias[col1], b2 = bias[col2];
#pragma unroll
                for (int j = 0; j < 4; j++) {
                    int s = (row + j) & (SS - 1);
                    float c  = cosT[s * 64 + d];
                    float sn = sinT[s * 64 + d];
                    float x1 = acc[mi][ni][j] + b1;
                    float x2 = acc[mi][ni + 2][j] + b2;
                    float o1 = x1 * c - x2 * sn;
                    float o2 = x2 * c + x1 * sn;
                    if (OUTMODE == 3) { o1 *= qscale; o2 *= qscale; }
                    ((bfloat*)C)[(size_t)(row + j) * N + col1] = (bfloat)o1;
                    ((bfloat*)C)[(size_t)(row + j) * N + col2] = (bfloat)o2;
                }
            }
        }
    }
}

// ---------------- Flash attention (causal), KVB=64 ----------------
// Q,K layout: (b, s, h*DH + d), Q pre-scaled.  Vt layout: (b, h, d, s).
// K double-buffered in swizzled LDS; V read direct from global (L2-hot).
// Grid: 1024 flat; 4 heads pinned per XCD, heavy q-blocks first.
__global__ __launch_bounds__(256, 3)
void attn_fwd(const bfloat* __restrict__ Q, const bfloat* __restrict__ K,
              const bfloat* __restrict__ Vt, bfloat* __restrict__ O) {
    __shared__ bfloat Ks[2][64 * 128];   // swizzled: 16B unit u ^= (row&7)
    __shared__ bfloat Pw[4][16 * 64];    // per-wave P, swizzled

    const int t = threadIdx.x, w = t >> 6, l = t & 63;
    const int lr = l & 15, lg = l >> 4;
    const int swz = (lr & 7) << 4;

    const int f = blockIdx.x;
    const int xcd = f & 7, slot = f >> 3;
    const int bh = xcd + 8 * (slot >> 5);       // 4 heads per XCD
    const int qidx = 31 - (slot & 31);          // heavy first
    const int b = bh >> 4, h = bh & 15;
    const int q0 = qidx * 64 + w * 16;

    const size_t bo_ = (size_t)b * SS * HH + (size_t)h * DHH;
    const bfloat* Qp = Q + bo_;
    const bfloat* Kp = K + bo_;
    const bfloat* Vp = Vt + (size_t)(b * NHH + h) * DHH * SS;
    bfloat* Op = O + bo_;

    auto stageK = [&](int buf, int kv0) {
#pragma unroll
        for (int i = 0; i < 4; i++) {
            int Ub = (i * 4 + w) * 64;
            int U = Ub + l;
            int r = U >> 4;
            int u = (U & 15) ^ (r & 7);
            gload_lds16(Kp + (size_t)(kv0 + r) * HH + u * 8, &Ks[buf][Ub * 8]);
        }
    };

    bf16x8 qf[4];
#pragma unroll
    for (int kt = 0; kt < 4; kt++)
        qf[kt] = *reinterpret_cast<const bf16x8*>(Qp + (size_t)(q0 + lr) * HH + kt * 32 + lg * 8);

    bf16x8 ones;
#pragma unroll
    for (int e = 0; e < 8; e++) ones[e] = (bfloat)1.0f;

    f32x4 o[8] = {};
    f32x4 lsv = {};
    float m[4];
#pragma unroll
    for (int j = 0; j < 4; j++) m[j] = -1e30f;

    const int nkv = qidx + 1;
    stageK(0, 0);
    __syncthreads();

    for (int kv = 0; kv < nkv; ++kv) {
        const int cur = kv & 1;

        // V fragments direct from global (issue first so prefetch stays newest)
        bf16x8 vfr[8][2];
#pragma unroll
        for (int nt = 0; nt < 8; nt++)
#pragma unroll
            for (int hk = 0; hk < 2; hk++)
                vfr[nt][hk] = *reinterpret_cast<const bf16x8*>(
                    Vp + (size_t)(nt * 16 + lr) * SS + kv * 64 + hk * 32 + lg * 8);

        if (kv + 1 < nkv) stageK(cur ^ 1, (kv + 1) * 64);

        const char* KB = (const char*)&Ks[cur][0];

        // QK^T: sc[kb]: k = kv*64 + kb*16 + lr, q = q0 + lg*4 + j
        f32x4 sc[4] = {};
        __builtin_amdgcn_s_setprio(1);
#pragma unroll
        for (int kt = 0; kt < 4; kt++) {
            const int col = (kt * 64 + lg * 16);
#pragma unroll
            for (int kb = 0; kb < 4; kb++) {
                bf16x8 kf = *reinterpret_cast<const bf16x8*>(
                    KB + (kb * 16 + lr) * 256 + (col ^ swz));
                sc[kb] = mfma16(qf[kt], kf, sc[kb]);
            }
        }
        __builtin_amdgcn_s_setprio(0);

        const bool diag = (kv == nkv - 1);
        float p[4][4], alpha[4];
        bool ga = false;
#pragma unroll
        for (int j = 0; j < 4; j++) {
            float v0 = sc[0][j], v1 = sc[1][j], v2 = sc[2][j], v3 = sc[3][j];
            if (diag) {
                int qr = q0 + lg * 4 + j;
                int k0 = kv * 64 + lr;
                if (k0      > qr) v0 = -1e30f;
                if (k0 + 16 > qr) v1 = -1e30f;
                if (k0 + 32 > qr) v2 = -1e30f;
                if (k0 + 48 > qr) v3 = -1e30f;
            }
            float mx = rowmax16(fmaxf(fmaxf(v0, v1), fmaxf(v2, v3)));
            bool grow = mx > m[j] + 8.0f;            // defer-max (T13)
            float mn = grow ? mx : m[j];
            alpha[j] = grow ? __expf(m[j] - mn) : 1.0f;
            m[j] = mn;
            ga = ga || grow;
            p[0][j] = __expf(v0 - mn);
            p[1][j] = __expf(v1 - mn);
            p[2][j] = __expf(v2 - mn);
            p[3][j] = __expf(v3 - mn);
        }
        if (__any(ga)) {
#pragma unroll
            for (int j = 0; j < 4; j++) {
                lsv[j] *= alpha[j];
#pragma unroll
                for (int nt = 0; nt < 8; nt++) o[nt][j] *= alpha[j];
            }
        }

        // write P (wave-private, swizzled): row q = lg*4+j, col k = kb*16+lr
        char* pwb = (char*)&Pw[w][0];
#pragma unroll
        for (int j = 0; j < 4; j++) {
            int q = lg * 4 + j;
            int qs = (q & 7) << 4;
#pragma unroll
            for (int kb = 0; kb < 4; kb++)
                *(bfloat*)(pwb + q * 128 + ((kb * 32 + lr * 2) ^ qs)) = (bfloat)p[kb][j];
        }
        asm volatile("s_waitcnt lgkmcnt(0)" ::: "memory");
        __builtin_amdgcn_sched_barrier(0);

        // PV + row-sum on the MFMA pipe
        const char* pwr = (const char*)&Pw[w][0];
        bf16x8 pa0 = *reinterpret_cast<const bf16x8*>(pwr + lr * 128 + ((lg * 16) ^ swz));
        bf16x8 pa1 = *reinterpret_cast<const bf16x8*>(pwr + lr * 128 + ((64 + lg * 16) ^ swz));
        __builtin_amdgcn_s_setprio(1);
        lsv = mfma16(pa0, ones, lsv);
        lsv = mfma16(pa1, ones, lsv);
#pragma unroll
        for (int nt = 0; nt < 8; nt++) {
            o[nt] = mfma16(pa0, vfr[nt][0], o[nt]);
            o[nt] = mfma16(pa1, vfr[nt][1], o[nt]);
        }
        __builtin_amdgcn_s_setprio(0);
        __syncthreads();
    }

#pragma unroll
    for (int j = 0; j < 4; j++) {
        float inv = 1.0f / lsv[j];
        int row = q0 + lg * 4 + j;
#pragma unroll
        for (int nt = 0; nt < 8; nt++)
            Op[(size_t)row * HH + nt * 16 + lr] = (bfloat)(o[nt][j] * inv);
    }
}

// ---------------- launch ----------------
extern "C" void kernel_launch(void* const* d_in, const int* in_sizes, int n_in,
                              void* d_out, int out_size, void* d_ws, size_t ws_size,
                              hipStream_t stream) {
    (void)in_sizes; (void)n_in; (void)out_size; (void)ws_size;
    const float* hs = (const float*)d_in[0];
    const float* Wq = (const float*)d_in[2];
    const float* bq = (const float*)d_in[3];
    const float* Wk = (const float*)d_in[4];
    const float* bk = (const float*)d_in[5];
    const float* Wv = (const float*)d_in[6];
    const float* bv = (const float*)d_in[7];
    const float* Wo = (const float*)d_in[8];
    const float* bo = (const float*)d_in[9];

    char* ws = (char*)d_ws;
    size_t off = 0;
    auto alloc = [&](size_t bytes) { void* p = ws + off; off += (bytes + 255) & ~(size_t)255; return p; };
    const size_t MK = (size_t)BB * SS * HH;   // 8M elems
    const size_t NK = (size_t)HH * HH;        // 4M elems

    bfloat* Xb  = (bfloat*)alloc(MK * 2);
    bfloat* Wqb = (bfloat*)alloc(NK * 2);
    bfloat* Wkb = (bfloat*)alloc(NK * 2);
    bfloat* Wvb = (bfloat*)alloc(NK * 2);
    bfloat* Wob = (bfloat*)alloc(NK * 2);
    bfloat* Qb  = (bfloat*)alloc(MK * 2);
    bfloat* Kb  = (bfloat*)alloc(MK * 2);
    bfloat* Vtb = (bfloat*)alloc(MK * 2);     // (b, h, d, s)
    float*  cosT = (float*)alloc((size_t)SS * 64 * 4);
    float*  sinT = (float*)alloc((size_t)SS * 64 * 4);
    bfloat* AOb = Xb;   // reuse: X no longer needed after V GEMM

    cvt_bf16<<<(int)(MK / 4 / 256), 256, 0, stream>>>(hs, Xb, (int)(MK / 4));
    cvt_bf16<<<(int)(NK / 4 / 256), 256, 0, stream>>>(Wq, Wqb, (int)(NK / 4));
    cvt_bf16<<<(int)(NK / 4 / 256), 256, 0, stream>>>(Wk, Wkb, (int)(NK / 4));
    cvt_bf16<<<(int)(NK / 4 / 256), 256, 0, stream>>>(Wv, Wvb, (int)(NK / 4));
    cvt_bf16<<<(int)(NK / 4 / 256), 256, 0, stream>>>(Wo, Wob, (int)(NK / 4));
    rope_table<<<(SS * 64 + 255) / 256, 256, 0, stream>>>(cosT, sinT);

    dim3 gg(BB * SS / 128, HH / 128);   // (32, 16)
    gemm_bt<3><<<gg, 256, 0, stream>>>(Xb, Wqb, bq, Qb, BB * SS, HH, HH, cosT, sinT);
    gemm_bt<4><<<gg, 256, 0, stream>>>(Xb, Wkb, bk, Kb, BB * SS, HH, HH, cosT, sinT);
    gemm_bt<2><<<gg, 256, 0, stream>>>(Xb, Wvb, bv, Vtb, BB * SS, HH, HH, nullptr, nullptr);

    attn_fwd<<<1024, 256, 0, stream>>>(Qb, Kb, Vtb, AOb);

    gemm_bt<1><<<gg, 256, 0, stream>>>(AOb, Wob, bo, d_out, BB * SS, HH, HH, nullptr, nullptr);
}

// Round 4
// 330.959 us; speedup vs baseline: 1.4740x; 1.4740x over previous
//
#include <hip/hip_runtime.h>
#include <hip/hip_bf16.h>
#include <cstdint>
#include <cstddef>

#define BB 2
#define SS 2048
#define HH 2048
#define NHH 16
#define DHH 128

using f32x4  = __attribute__((ext_vector_type(4))) float;
using bf16x8 = __attribute__((ext_vector_type(8))) __bf16;
using bf16x4 = __attribute__((ext_vector_type(4))) __bf16;
using bfloat = __bf16;

__device__ inline void gload_lds16(const void* g, void* l) {
    __builtin_amdgcn_global_load_lds(
        (const __attribute__((address_space(1))) void*)g,
        (__attribute__((address_space(3))) void*)l, 16, 0, 0);
}

__device__ inline f32x4 mfma16(bf16x8 a, bf16x8 b, f32x4 c) {
    return __builtin_amdgcn_mfma_f32_16x16x32_bf16(a, b, c, 0, 0, 0);
}

template <int CTRL>
__device__ inline float dpp_max_step(float x) {
    int y = __builtin_amdgcn_update_dpp(0, __builtin_bit_cast(int, x), CTRL, 0xf, 0xf, false);
    return fmaxf(x, __builtin_bit_cast(float, y));
}
// max over the 16-lane row group (lanes lr=0..15 within each lg group)
__device__ inline float rowmax16(float x) {
    x = dpp_max_step<0x121>(x);   // row_ror:1
    x = dpp_max_step<0x122>(x);   // row_ror:2
    x = dpp_max_step<0x124>(x);   // row_ror:4
    x = dpp_max_step<0x128>(x);   // row_ror:8
    return x;
}

// ---------------- fp32 -> bf16 conversion ----------------
__global__ void cvt_bf16(const float* __restrict__ in, bfloat* __restrict__ out, int n4) {
    int i = blockIdx.x * blockDim.x + threadIdx.x;
    if (i >= n4) return;
    float4 v = reinterpret_cast<const float4*>(in)[i];
    bf16x4 o;
    o[0] = (bfloat)v.x; o[1] = (bfloat)v.y; o[2] = (bfloat)v.z; o[3] = (bfloat)v.w;
    reinterpret_cast<bf16x4*>(out)[i] = o;
}

// ---------------- RoPE tables (S x 64) ----------------
__global__ void rope_table(float* __restrict__ cosT, float* __restrict__ sinT) {
    int i = blockIdx.x * blockDim.x + threadIdx.x;
    if (i >= SS * 64) return;
    int s = i >> 6, j = i & 63;
    float invf = powf(10000.0f, -(float)j / 64.0f);
    float ang = (float)s * invf;
    cosT[i] = cosf(ang);
    sinT[i] = sinf(ang);
}

// ---------------- GEMM: C(MxN) = A(MxK) * Bt(NxK)^T + bias ----------------
// OUTMODE: 0 = bf16 row-major, 1 = f32 row-major, 2 = bf16 V-transposed (b,h,d,s)
//          3 = bf16 row-major + RoPE + 1/sqrt(DH) scale (Q), 4 = bf16 + RoPE (K)
template <int OUTMODE>
__global__ __launch_bounds__(256, 2)
void gemm_bt(const bfloat* __restrict__ A, const bfloat* __restrict__ Bt,
             const float* __restrict__ bias, void* __restrict__ C,
             int M, int N, int K,
             const float* __restrict__ cosT, const float* __restrict__ sinT) {
    constexpr int BM = 128, BN = 128, BK = 32;
    __shared__ bfloat As[BM * BK];
    __shared__ bfloat Bs[BN * BK];
    const int t = threadIdx.x, w = t >> 6, l = t & 63;
    const int lr = l & 15, lg = l >> 4;
    const int m0 = blockIdx.x * BM, n0 = blockIdx.y * BN;
    const int wm = (w >> 1) * 64;
    const int base = (t & ~63) * 8;   // wave-uniform LDS element base

    f32x4 acc[4][4] = {};

    for (int kb = 0; kb < K; kb += BK) {
#pragma unroll
        for (int i = 0; i < 2; i++) {
            int idx = i * 256 + t;
            int r = idx >> 2, k8 = (idx & 3) << 3;
            gload_lds16(A  + (size_t)(m0 + r) * K + kb + k8, As + (i * 2048 + base));
            gload_lds16(Bt + (size_t)(n0 + r) * K + kb + k8, Bs + (i * 2048 + base));
        }
        __syncthreads();
        bf16x8 af[4], bfr[4];
#pragma unroll
        for (int mi = 0; mi < 4; mi++)
            af[mi] = *reinterpret_cast<const bf16x8*>(&As[(wm + mi * 16 + lr) * BK + lg * 8]);
#pragma unroll
        for (int ni = 0; ni < 4; ni++) {
            int cb = (w & 1) * 32 + (ni & 1) * 16 + (ni >> 1) * 64;
            bfr[ni] = *reinterpret_cast<const bf16x8*>(&Bs[(cb + lr) * BK + lg * 8]);
        }
#pragma unroll
        for (int mi = 0; mi < 4; mi++)
#pragma unroll
            for (int ni = 0; ni < 4; ni++)
                acc[mi][ni] = mfma16(af[mi], bfr[ni], acc[mi][ni]);
        __syncthreads();
    }

    if (OUTMODE <= 2) {
#pragma unroll
        for (int mi = 0; mi < 4; mi++) {
            int row = m0 + wm + mi * 16 + lg * 4;
#pragma unroll
            for (int ni = 0; ni < 4; ni++) {
                int cb = (w & 1) * 32 + (ni & 1) * 16 + (ni >> 1) * 64;
                int col = n0 + cb + lr;
                float bv = bias[col];
#pragma unroll
                for (int j = 0; j < 4; j++) {
                    float v = acc[mi][ni][j] + bv;
                    if (OUTMODE == 1) {
                        ((float*)C)[(size_t)(row + j) * N + col] = v;
                    } else if (OUTMODE == 0) {
                        ((bfloat*)C)[(size_t)(row + j) * N + col] = (bfloat)v;
                    } else {
                        int bb = (row + j) >> 11;
                        int s  = (row + j) & (SS - 1);
                        ((bfloat*)C)[((size_t)(bb * HH + col)) * SS + s] = (bfloat)v;
                    }
                }
            }
        }
    } else {
        const float qscale = 0.088388347648318447f;   // 1/sqrt(128)
#pragma unroll
        for (int mi = 0; mi < 4; mi++) {
            int row = m0 + wm + mi * 16 + lg * 4;
#pragma unroll
            for (int ni = 0; ni < 2; ni++) {
                int d = (w & 1) * 32 + ni * 16 + lr;      // 0..63 within head
                int col1 = n0 + d, col2 = col1 + 64;
                float b1 = bias[col1], b2 = bias[col2];
#pragma unroll
                for (int j = 0; j < 4; j++) {
                    int s = (row + j) & (SS - 1);
                    float c  = cosT[s * 64 + d];
                    float sn = sinT[s * 64 + d];
                    float x1 = acc[mi][ni][j] + b1;
                    float x2 = acc[mi][ni + 2][j] + b2;
                    float o1 = x1 * c - x2 * sn;
                    float o2 = x2 * c + x1 * sn;
                    if (OUTMODE == 3) { o1 *= qscale; o2 *= qscale; }
                    ((bfloat*)C)[(size_t)(row + j) * N + col1] = (bfloat)o1;
                    ((bfloat*)C)[(size_t)(row + j) * N + col2] = (bfloat)o2;
                }
            }
        }
    }
}

// ---------------- Flash attention (causal), KVB=64, K+V double-buffered LDS ----
// Q,K layout: (b, s, h*DH + d), Q pre-scaled.  Vt layout: (b, h, d, s).
// Grid: 1024 flat; 4 heads pinned per XCD, heavy q-blocks first.
__global__ __launch_bounds__(256, 2)
void attn_fwd(const bfloat* __restrict__ Q, const bfloat* __restrict__ K,
              const bfloat* __restrict__ Vt, bfloat* __restrict__ O) {
    __shared__ bfloat Ks[2][64 * 128];   // swizzled: 16B unit u ^= (row&7)
    __shared__ bfloat Vs[2][128 * 64];   // rows = d, cols = k, swizzled
    __shared__ bfloat Pw[4][16 * 64];    // per-wave P, swizzled

    const int t = threadIdx.x, w = t >> 6, l = t & 63;
    const int lr = l & 15, lg = l >> 4;
    const int swz = (lr & 7) << 4;

    const int f = blockIdx.x;
    const int xcd = f & 7, slot = f >> 3;
    const int bh = xcd + 8 * (slot >> 5);       // 4 heads per XCD
    const int qidx = 31 - (slot & 31);          // heavy first
    const int b = bh >> 4, h = bh & 15;
    const int q0 = qidx * 64 + w * 16;

    const size_t bo_ = (size_t)b * SS * HH + (size_t)h * DHH;
    const bfloat* Qp = Q + bo_;
    const bfloat* Kp = K + bo_;
    const bfloat* Vp = Vt + (size_t)(b * NHH + h) * DHH * SS;
    bfloat* Op = O + bo_;

    // stage K tile (64 x 128) and V tile (128 d x 64 k), source pre-swizzled
    auto stage = [&](int buf, int kv0) {
#pragma unroll
        for (int i = 0; i < 4; i++) {
            int Ub = (i * 4 + w) * 64;
            int U = Ub + l;
            int r = U >> 4;
            int u = (U & 15) ^ (r & 7);
            gload_lds16(Kp + (size_t)(kv0 + r) * HH + u * 8, &Ks[buf][Ub * 8]);
        }
#pragma unroll
        for (int i = 0; i < 4; i++) {
            int Ub = (i * 4 + w) * 64;
            int U = Ub + l;
            int r = U >> 3;
            int u = (U & 7) ^ (r & 7);
            gload_lds16(Vp + (size_t)r * SS + kv0 + u * 8, &Vs[buf][Ub * 8]);
        }
    };

    bf16x8 qf[4];
#pragma unroll
    for (int kt = 0; kt < 4; kt++)
        qf[kt] = *reinterpret_cast<const bf16x8*>(Qp + (size_t)(q0 + lr) * HH + kt * 32 + lg * 8);

    bf16x8 ones;
#pragma unroll
    for (int e = 0; e < 8; e++) ones[e] = (bfloat)1.0f;

    f32x4 o[8] = {};
    f32x4 lsv = {};
    float m[4];
#pragma unroll
    for (int j = 0; j < 4; j++) m[j] = -1e30f;

    const int nkv = qidx + 1;
    stage(0, 0);
    __syncthreads();

    for (int kv = 0; kv < nkv; ++kv) {
        const int cur = kv & 1;
        if (kv + 1 < nkv) stage(cur ^ 1, (kv + 1) * 64);

        const char* KB = (const char*)&Ks[cur][0];
        const char* VB = (const char*)&Vs[cur][0];

        // QK^T: sc[kb]: k = kv*64 + kb*16 + lr, q = q0 + lg*4 + j
        f32x4 sc[4] = {};
        __builtin_amdgcn_s_setprio(1);
#pragma unroll
        for (int kt = 0; kt < 4; kt++) {
            const int col = (kt * 64 + lg * 16);
#pragma unroll
            for (int kb = 0; kb < 4; kb++) {
                bf16x8 kf = *reinterpret_cast<const bf16x8*>(
                    KB + (kb * 16 + lr) * 256 + (col ^ swz));
                sc[kb] = mfma16(qf[kt], kf, sc[kb]);
            }
        }
        __builtin_amdgcn_s_setprio(0);

        const bool diag = (kv == nkv - 1);
        float p[4][4], alpha[4];
        bool ga = false;
#pragma unroll
        for (int j = 0; j < 4; j++) {
            float v0 = sc[0][j], v1 = sc[1][j], v2 = sc[2][j], v3 = sc[3][j];
            if (diag) {
                int qr = q0 + lg * 4 + j;
                int k0 = kv * 64 + lr;
                if (k0      > qr) v0 = -1e30f;
                if (k0 + 16 > qr) v1 = -1e30f;
                if (k0 + 32 > qr) v2 = -1e30f;
                if (k0 + 48 > qr) v3 = -1e30f;
            }
            float mx = rowmax16(fmaxf(fmaxf(v0, v1), fmaxf(v2, v3)));
            bool grow = mx > m[j] + 8.0f;            // defer-max (T13)
            float mn = grow ? mx : m[j];
            alpha[j] = grow ? __expf(m[j] - mn) : 1.0f;
            m[j] = mn;
            ga = ga || grow;
            p[0][j] = __expf(v0 - mn);
            p[1][j] = __expf(v1 - mn);
            p[2][j] = __expf(v2 - mn);
            p[3][j] = __expf(v3 - mn);
        }
        if (__any(ga)) {
#pragma unroll
            for (int j = 0; j < 4; j++) {
                lsv[j] *= alpha[j];
#pragma unroll
                for (int nt = 0; nt < 8; nt++) o[nt][j] *= alpha[j];
            }
        }

        // write P (wave-private, swizzled): row q = lg*4+j, col k = kb*16+lr
        char* pwb = (char*)&Pw[w][0];
#pragma unroll
        for (int j = 0; j < 4; j++) {
            int q = lg * 4 + j;
            int qs = (q & 7) << 4;
#pragma unroll
            for (int kb = 0; kb < 4; kb++)
                *(bfloat*)(pwb + q * 128 + ((kb * 32 + lr * 2) ^ qs)) = (bfloat)p[kb][j];
        }
        asm volatile("s_waitcnt lgkmcnt(0)" ::: "memory");
        __builtin_amdgcn_sched_barrier(0);

        // PV + row-sum on the MFMA pipe
        const char* pwr = (const char*)&Pw[w][0];
        bf16x8 pa0 = *reinterpret_cast<const bf16x8*>(pwr + lr * 128 + ((lg * 16) ^ swz));
        bf16x8 pa1 = *reinterpret_cast<const bf16x8*>(pwr + lr * 128 + ((64 + lg * 16) ^ swz));
        __builtin_amdgcn_s_setprio(1);
        lsv = mfma16(pa0, ones, lsv);
        lsv = mfma16(pa1, ones, lsv);
#pragma unroll
        for (int nt = 0; nt < 8; nt++) {
            const char* vb = VB + (nt * 16 + lr) * 128;
            bf16x8 vf0 = *reinterpret_cast<const bf16x8*>(vb + ((lg * 16) ^ swz));
            bf16x8 vf1 = *reinterpret_cast<const bf16x8*>(vb + ((64 + lg * 16) ^ swz));
            o[nt] = mfma16(pa0, vf0, o[nt]);
            o[nt] = mfma16(pa1, vf1, o[nt]);
        }
        __builtin_amdgcn_s_setprio(0);
        __syncthreads();
    }

#pragma unroll
    for (int j = 0; j < 4; j++) {
        float inv = 1.0f / lsv[j];
        int row = q0 + lg * 4 + j;
#pragma unroll
        for (int nt = 0; nt < 8; nt++)
            Op[(size_t)row * HH + nt * 16 + lr] = (bfloat)(o[nt][j] * inv);
    }
}

// ---------------- launch ----------------
extern "C" void kernel_launch(void* const* d_in, const int* in_sizes, int n_in,
                              void* d_out, int out_size, void* d_ws, size_t ws_size,
                              hipStream_t stream) {
    (void)in_sizes; (void)n_in; (void)out_size; (void)ws_size;
    const float* hs = (const float*)d_in[0];
    const float* Wq = (const float*)d_in[2];
    const float* bq = (const float*)d_in[3];
    const float* Wk = (const float*)d_in[4];
    const float* bk = (const float*)d_in[5];
    const float* Wv = (const float*)d_in[6];
    const float* bv = (const float*)d_in[7];
    const float* Wo = (const float*)d_in[8];
    const float* bo = (const float*)d_in[9];

    char* ws = (char*)d_ws;
    size_t off = 0;
    auto alloc = [&](size_t bytes) { void* p = ws + off; off += (bytes + 255) & ~(size_t)255; return p; };
    const size_t MK = (size_t)BB * SS * HH;   // 8M elems
    const size_t NK = (size_t)HH * HH;        // 4M elems

    bfloat* Xb  = (bfloat*)alloc(MK * 2);
    bfloat* Wqb = (bfloat*)alloc(NK * 2);
    bfloat* Wkb = (bfloat*)alloc(NK * 2);
    bfloat* Wvb = (bfloat*)alloc(NK * 2);
    bfloat* Wob = (bfloat*)alloc(NK * 2);
    bfloat* Qb  = (bfloat*)alloc(MK * 2);
    bfloat* Kb  = (bfloat*)alloc(MK * 2);
    bfloat* Vtb = (bfloat*)alloc(MK * 2);     // (b, h, d, s)
    float*  cosT = (float*)alloc((size_t)SS * 64 * 4);
    float*  sinT = (float*)alloc((size_t)SS * 64 * 4);
    bfloat* AOb = Xb;   // reuse: X no longer needed after V GEMM

    cvt_bf16<<<(int)(MK / 4 / 256), 256, 0, stream>>>(hs, Xb, (int)(MK / 4));
    cvt_bf16<<<(int)(NK / 4 / 256), 256, 0, stream>>>(Wq, Wqb, (int)(NK / 4));
    cvt_bf16<<<(int)(NK / 4 / 256), 256, 0, stream>>>(Wk, Wkb, (int)(NK / 4));
    cvt_bf16<<<(int)(NK / 4 / 256), 256, 0, stream>>>(Wv, Wvb, (int)(NK / 4));
    cvt_bf16<<<(int)(NK / 4 / 256), 256, 0, stream>>>(Wo, Wob, (int)(NK / 4));
    rope_table<<<(SS * 64 + 255) / 256, 256, 0, stream>>>(cosT, sinT);

    dim3 gg(BB * SS / 128, HH / 128);   // (32, 16)
    gemm_bt<3><<<gg, 256, 0, stream>>>(Xb, Wqb, bq, Qb, BB * SS, HH, HH, cosT, sinT);
    gemm_bt<4><<<gg, 256, 0, stream>>>(Xb, Wkb, bk, Kb, BB * SS, HH, HH, cosT, sinT);
    gemm_bt<2><<<gg, 256, 0, stream>>>(Xb, Wvb, bv, Vtb, BB * SS, HH, HH, nullptr, nullptr);

    attn_fwd<<<1024, 256, 0, stream>>>(Qb, Kb, Vtb, AOb);

    gemm_bt<1><<<gg, 256, 0, stream>>>(AOb, Wob, bo, d_out, BB * SS, HH, HH, nullptr, nullptr);
}

// Round 5
// 308.777 us; speedup vs baseline: 1.5799x; 1.0718x over previous
//
#include <hip/hip_runtime.h>
#include <hip/hip_bf16.h>
#include <cstdint>
#include <cstddef>

#define BB 2
#define SS 2048
#define HH 2048
#define NHH 16
#define DHH 128

using f32x4  = __attribute__((ext_vector_type(4))) float;
using bf16x8 = __attribute__((ext_vector_type(8))) __bf16;
using bf16x4 = __attribute__((ext_vector_type(4))) __bf16;
using bfloat = __bf16;

__device__ inline void gload_lds16(const void* g, void* l) {
    __builtin_amdgcn_global_load_lds(
        (const __attribute__((address_space(1))) void*)g,
        (__attribute__((address_space(3))) void*)l, 16, 0, 0);
}

__device__ inline f32x4 mfma16(bf16x8 a, bf16x8 b, f32x4 c) {
    return __builtin_amdgcn_mfma_f32_16x16x32_bf16(a, b, c, 0, 0, 0);
}

template <int CTRL>
__device__ inline float dpp_max_step(float x) {
    int y = __builtin_amdgcn_update_dpp(0, __builtin_bit_cast(int, x), CTRL, 0xf, 0xf, false);
    return fmaxf(x, __builtin_bit_cast(float, y));
}
// max over the 16-lane row group (lanes lr=0..15 within each lg group)
__device__ inline float rowmax16(float x) {
    x = dpp_max_step<0x121>(x);   // row_ror:1
    x = dpp_max_step<0x122>(x);   // row_ror:2
    x = dpp_max_step<0x124>(x);   // row_ror:4
    x = dpp_max_step<0x128>(x);   // row_ror:8
    return x;
}

// ---------------- fp32 -> bf16 conversion ----------------
__global__ void cvt_bf16(const float* __restrict__ in, bfloat* __restrict__ out, int n4) {
    int i = blockIdx.x * blockDim.x + threadIdx.x;
    if (i >= n4) return;
    float4 v = reinterpret_cast<const float4*>(in)[i];
    bf16x4 o;
    o[0] = (bfloat)v.x; o[1] = (bfloat)v.y; o[2] = (bfloat)v.z; o[3] = (bfloat)v.w;
    reinterpret_cast<bf16x4*>(out)[i] = o;
}

// fused conversion of the 4 weight matrices (4096 blocks each)
__global__ void cvt_bf16_w(const float* __restrict__ s0, const float* __restrict__ s1,
                           const float* __restrict__ s2, const float* __restrict__ s3,
                           bfloat* __restrict__ d0, bfloat* __restrict__ d1,
                           bfloat* __restrict__ d2, bfloat* __restrict__ d3) {
    int sel = blockIdx.x >> 12;
    int i = (blockIdx.x & 4095) * 256 + threadIdx.x;
    const float* s = sel == 0 ? s0 : sel == 1 ? s1 : sel == 2 ? s2 : s3;
    bfloat* d = sel == 0 ? d0 : sel == 1 ? d1 : sel == 2 ? d2 : d3;
    float4 v = reinterpret_cast<const float4*>(s)[i];
    bf16x4 o;
    o[0] = (bfloat)v.x; o[1] = (bfloat)v.y; o[2] = (bfloat)v.z; o[3] = (bfloat)v.w;
    reinterpret_cast<bf16x4*>(d)[i] = o;
}

// ---------------- RoPE tables (S x 64) ----------------
__global__ void rope_table(float* __restrict__ cosT, float* __restrict__ sinT) {
    int i = blockIdx.x * blockDim.x + threadIdx.x;
    if (i >= SS * 64) return;
    int s = i >> 6, j = i & 63;
    float invf = powf(10000.0f, -(float)j / 64.0f);
    float ang = (float)s * invf;
    cosT[i] = cosf(ang);
    sinT[i] = sinf(ang);
}

// ================= fused QKV GEMM =================
// grid (32, 48): blockIdx.y>>4 selects {Q, K, V}; each 128-col tile sits in one weight.
// Q: bf16 row-major + RoPE + 1/sqrt(DH); K: bf16 row-major + RoPE; V: bf16 (b,h,d,s).
__global__ __launch_bounds__(256, 2)
void gemm_qkv(const bfloat* __restrict__ A,
              const bfloat* __restrict__ Bq, const bfloat* __restrict__ Bk,
              const bfloat* __restrict__ Bv,
              const float* __restrict__ bq, const float* __restrict__ bk,
              const float* __restrict__ bv,
              bfloat* __restrict__ Qo, bfloat* __restrict__ Ko, bfloat* __restrict__ Vto,
              const float* __restrict__ cosT, const float* __restrict__ sinT) {
    constexpr int BM = 128, BN = 128, BK = 32, K = HH, N = HH;
    __shared__ bfloat As[BM * BK];
    __shared__ bfloat Bs[BN * BK];
    const int t = threadIdx.x, w = t >> 6, l = t & 63;
    const int lr = l & 15, lg = l >> 4;
    const int sel = blockIdx.y >> 4;
    const bfloat* Bt = sel == 0 ? Bq : sel == 1 ? Bk : Bv;
    const float* bias = sel == 0 ? bq : sel == 1 ? bk : bv;
    const int m0 = blockIdx.x * BM, n0 = (blockIdx.y & 15) * BN;
    const int wm = (w >> 1) * 64;
    const int base = (t & ~63) * 8;

    f32x4 acc[4][4] = {};

    for (int kb = 0; kb < K; kb += BK) {
#pragma unroll
        for (int i = 0; i < 2; i++) {
            int idx = i * 256 + t;
            int r = idx >> 2, k8 = (idx & 3) << 3;
            gload_lds16(A  + (size_t)(m0 + r) * K + kb + k8, As + (i * 2048 + base));
            gload_lds16(Bt + (size_t)(n0 + r) * K + kb + k8, Bs + (i * 2048 + base));
        }
        __syncthreads();
        bf16x8 af[4], bfr[4];
#pragma unroll
        for (int mi = 0; mi < 4; mi++)
            af[mi] = *reinterpret_cast<const bf16x8*>(&As[(wm + mi * 16 + lr) * BK + lg * 8]);
#pragma unroll
        for (int ni = 0; ni < 4; ni++) {
            int cb = (w & 1) * 32 + (ni & 1) * 16 + (ni >> 1) * 64;
            bfr[ni] = *reinterpret_cast<const bf16x8*>(&Bs[(cb + lr) * BK + lg * 8]);
        }
#pragma unroll
        for (int mi = 0; mi < 4; mi++)
#pragma unroll
            for (int ni = 0; ni < 4; ni++)
                acc[mi][ni] = mfma16(af[mi], bfr[ni], acc[mi][ni]);
        __syncthreads();
    }

    if (sel == 2) {   // V: write transposed (b, h, d, s)
#pragma unroll
        for (int mi = 0; mi < 4; mi++) {
            int row = m0 + wm + mi * 16 + lg * 4;
#pragma unroll
            for (int ni = 0; ni < 4; ni++) {
                int cb = (w & 1) * 32 + (ni & 1) * 16 + (ni >> 1) * 64;
                int col = n0 + cb + lr;
                float bv_ = bias[col];
#pragma unroll
                for (int j = 0; j < 4; j++) {
                    float v = acc[mi][ni][j] + bv_;
                    int bb = (row + j) >> 11;
                    int s  = (row + j) & (SS - 1);
                    Vto[((size_t)(bb * HH + col)) * SS + s] = (bfloat)v;
                }
            }
        }
    } else {          // Q/K: RoPE epilogue (Q also scaled)
        bfloat* C = sel == 0 ? Qo : Ko;
        const float qscale = sel == 0 ? 0.088388347648318447f : 1.0f;
#pragma unroll
        for (int mi = 0; mi < 4; mi++) {
            int row = m0 + wm + mi * 16 + lg * 4;
#pragma unroll
            for (int ni = 0; ni < 2; ni++) {
                int d = (w & 1) * 32 + ni * 16 + lr;      // 0..63 within head
                int col1 = n0 + d, col2 = col1 + 64;
                float b1 = bias[col1], b2 = bias[col2];
#pragma unroll
                for (int j = 0; j < 4; j++) {
                    int s = (row + j) & (SS - 1);
                    float c  = cosT[s * 64 + d];
                    float sn = sinT[s * 64 + d];
                    float x1 = acc[mi][ni][j] + b1;
                    float x2 = acc[mi][ni + 2][j] + b2;
                    float o1 = (x1 * c - x2 * sn) * qscale;
                    float o2 = (x2 * c + x1 * sn) * qscale;
                    C[(size_t)(row + j) * N + col1] = (bfloat)o1;
                    C[(size_t)(row + j) * N + col2] = (bfloat)o2;
                }
            }
        }
    }
}

// ---------------- out-proj GEMM: C(MxN) f32 = A(MxK) * Bt(NxK)^T + bias ----------------
__global__ __launch_bounds__(256, 2)
void gemm_out(const bfloat* __restrict__ A, const bfloat* __restrict__ Bt,
              const float* __restrict__ bias, float* __restrict__ C,
              int M, int N, int K) {
    constexpr int BM = 128, BN = 128, BK = 32;
    __shared__ bfloat As[BM * BK];
    __shared__ bfloat Bs[BN * BK];
    const int t = threadIdx.x, w = t >> 6, l = t & 63;
    const int lr = l & 15, lg = l >> 4;
    const int m0 = blockIdx.x * BM, n0 = blockIdx.y * BN;
    const int wm = (w >> 1) * 64;
    const int base = (t & ~63) * 8;

    f32x4 acc[4][4] = {};

    for (int kb = 0; kb < K; kb += BK) {
#pragma unroll
        for (int i = 0; i < 2; i++) {
            int idx = i * 256 + t;
            int r = idx >> 2, k8 = (idx & 3) << 3;
            gload_lds16(A  + (size_t)(m0 + r) * K + kb + k8, As + (i * 2048 + base));
            gload_lds16(Bt + (size_t)(n0 + r) * K + kb + k8, Bs + (i * 2048 + base));
        }
        __syncthreads();
        bf16x8 af[4], bfr[4];
#pragma unroll
        for (int mi = 0; mi < 4; mi++)
            af[mi] = *reinterpret_cast<const bf16x8*>(&As[(wm + mi * 16 + lr) * BK + lg * 8]);
#pragma unroll
        for (int ni = 0; ni < 4; ni++) {
            int cb = (w & 1) * 32 + (ni & 1) * 16 + (ni >> 1) * 64;
            bfr[ni] = *reinterpret_cast<const bf16x8*>(&Bs[(cb + lr) * BK + lg * 8]);
        }
#pragma unroll
        for (int mi = 0; mi < 4; mi++)
#pragma unroll
            for (int ni = 0; ni < 4; ni++)
                acc[mi][ni] = mfma16(af[mi], bfr[ni], acc[mi][ni]);
        __syncthreads();
    }

#pragma unroll
    for (int mi = 0; mi < 4; mi++) {
        int row = m0 + wm + mi * 16 + lg * 4;
#pragma unroll
        for (int ni = 0; ni < 4; ni++) {
            int cb = (w & 1) * 32 + (ni & 1) * 16 + (ni >> 1) * 64;
            int col = n0 + cb + lr;
            float bv = bias[col];
#pragma unroll
            for (int j = 0; j < 4; j++)
                C[(size_t)(row + j) * N + col] = acc[mi][ni][j] + bv;
        }
    }
}

// ---------------- Flash attention (causal), KVB=64, single-buffered LDS ----
// Q,K layout: (b, s, h*DH + d), Q pre-scaled.  Vt layout: (b, h, d, s).
// Grid: 1024 flat; 4 heads pinned per XCD, heavy q-blocks first. 4 blocks/CU.
__global__ __launch_bounds__(256, 4)
void attn_fwd(const bfloat* __restrict__ Q, const bfloat* __restrict__ K,
              const bfloat* __restrict__ Vt, bfloat* __restrict__ O) {
    __shared__ bfloat Ks[64 * 128];   // swizzled: 16B unit u ^= (row&7)
    __shared__ bfloat Vs[128 * 64];   // rows = d, cols = k, swizzled
    __shared__ bfloat Pw[4][16 * 64]; // per-wave P, swizzled

    const int t = threadIdx.x, w = t >> 6, l = t & 63;
    const int lr = l & 15, lg = l >> 4;
    const int swz = (lr & 7) << 4;

    const int f = blockIdx.x;
    const int xcd = f & 7, slot = f >> 3;
    const int bh = xcd + 8 * (slot >> 5);       // 4 heads per XCD
    const int qidx = 31 - (slot & 31);          // heavy first
    const int b = bh >> 4, h = bh & 15;
    const int q0 = qidx * 64 + w * 16;

    const size_t bo_ = (size_t)b * SS * HH + (size_t)h * DHH;
    const bfloat* Qp = Q + bo_;
    const bfloat* Kp = K + bo_;
    const bfloat* Vp = Vt + (size_t)(b * NHH + h) * DHH * SS;
    bfloat* Op = O + bo_;

    // stage K tile (64 x 128) and V tile (128 d x 64 k), source pre-swizzled
    auto stage = [&](int kv0) {
#pragma unroll
        for (int i = 0; i < 4; i++) {
            int Ub = (i * 4 + w) * 64;
            int U = Ub + l;
            int r = U >> 4;
            int u = (U & 15) ^ (r & 7);
            gload_lds16(Kp + (size_t)(kv0 + r) * HH + u * 8, &Ks[Ub * 8]);
        }
#pragma unroll
        for (int i = 0; i < 4; i++) {
            int Ub = (i * 4 + w) * 64;
            int U = Ub + l;
            int r = U >> 3;
            int u = (U & 7) ^ (r & 7);
            gload_lds16(Vp + (size_t)r * SS + kv0 + u * 8, &Vs[Ub * 8]);
        }
    };

    bf16x8 qf[4];
#pragma unroll
    for (int kt = 0; kt < 4; kt++)
        qf[kt] = *reinterpret_cast<const bf16x8*>(Qp + (size_t)(q0 + lr) * HH + kt * 32 + lg * 8);

    bf16x8 ones;
#pragma unroll
    for (int e = 0; e < 8; e++) ones[e] = (bfloat)1.0f;

    f32x4 o[8] = {};
    f32x4 lsv = {};
    float m[4];
#pragma unroll
    for (int j = 0; j < 4; j++) m[j] = -1e30f;

    const int nkv = qidx + 1;

    for (int kv = 0; kv < nkv; ++kv) {
        stage(kv * 64);
        __syncthreads();                         // drains vmcnt: tiles ready

        const char* KB = (const char*)&Ks[0];
        const char* VB = (const char*)&Vs[0];

        // QK^T: sc[kb]: k = kv*64 + kb*16 + lr, q = q0 + lg*4 + j
        f32x4 sc[4] = {};
        __builtin_amdgcn_s_setprio(1);
#pragma unroll
        for (int kt = 0; kt < 4; kt++) {
            const int col = (kt * 64 + lg * 16);
#pragma unroll
            for (int kb = 0; kb < 4; kb++) {
                bf16x8 kf = *reinterpret_cast<const bf16x8*>(
                    KB + (kb * 16 + lr) * 256 + (col ^ swz));
                sc[kb] = mfma16(qf[kt], kf, sc[kb]);
            }
        }
        __builtin_amdgcn_s_setprio(0);

        const bool diag = (kv == nkv - 1);
        float p[4][4], alpha[4];
        bool ga = false;
#pragma unroll
        for (int j = 0; j < 4; j++) {
            float v0 = sc[0][j], v1 = sc[1][j], v2 = sc[2][j], v3 = sc[3][j];
            if (diag) {
                int qr = q0 + lg * 4 + j;
                int k0 = kv * 64 + lr;
                if (k0      > qr) v0 = -1e30f;
                if (k0 + 16 > qr) v1 = -1e30f;
                if (k0 + 32 > qr) v2 = -1e30f;
                if (k0 + 48 > qr) v3 = -1e30f;
            }
            float mx = rowmax16(fmaxf(fmaxf(v0, v1), fmaxf(v2, v3)));
            bool grow = mx > m[j] + 8.0f;            // defer-max (T13)
            float mn = grow ? mx : m[j];
            alpha[j] = grow ? __expf(m[j] - mn) : 1.0f;
            m[j] = mn;
            ga = ga || grow;
            p[0][j] = __expf(v0 - mn);
            p[1][j] = __expf(v1 - mn);
            p[2][j] = __expf(v2 - mn);
            p[3][j] = __expf(v3 - mn);
        }
        if (__any(ga)) {
#pragma unroll
            for (int j = 0; j < 4; j++) {
                lsv[j] *= alpha[j];
#pragma unroll
                for (int nt = 0; nt < 8; nt++) o[nt][j] *= alpha[j];
            }
        }

        // write P (wave-private, swizzled): row q = lg*4+j, col k = kb*16+lr
        char* pwb = (char*)&Pw[w][0];
#pragma unroll
        for (int j = 0; j < 4; j++) {
            int q = lg * 4 + j;
            int qs = (q & 7) << 4;
#pragma unroll
            for (int kb = 0; kb < 4; kb++)
                *(bfloat*)(pwb + q * 128 + ((kb * 32 + lr * 2) ^ qs)) = (bfloat)p[kb][j];
        }
        asm volatile("s_waitcnt lgkmcnt(0)" ::: "memory");
        __builtin_amdgcn_sched_barrier(0);

        // PV + row-sum on the MFMA pipe
        const char* pwr = (const char*)&Pw[w][0];
        bf16x8 pa0 = *reinterpret_cast<const bf16x8*>(pwr + lr * 128 + ((lg * 16) ^ swz));
        bf16x8 pa1 = *reinterpret_cast<const bf16x8*>(pwr + lr * 128 + ((64 + lg * 16) ^ swz));
        __builtin_amdgcn_s_setprio(1);
        lsv = mfma16(pa0, ones, lsv);
        lsv = mfma16(pa1, ones, lsv);
#pragma unroll
        for (int nt = 0; nt < 8; nt++) {
            const char* vb = VB + (nt * 16 + lr) * 128;
            bf16x8 vf0 = *reinterpret_cast<const bf16x8*>(vb + ((lg * 16) ^ swz));
            bf16x8 vf1 = *reinterpret_cast<const bf16x8*>(vb + ((64 + lg * 16) ^ swz));
            o[nt] = mfma16(pa0, vf0, o[nt]);
            o[nt] = mfma16(pa1, vf1, o[nt]);
        }
        __builtin_amdgcn_s_setprio(0);
        __syncthreads();                         // LDS reads done before restage
    }

#pragma unroll
    for (int j = 0; j < 4; j++) {
        float inv = 1.0f / lsv[j];
        int row = q0 + lg * 4 + j;
#pragma unroll
        for (int nt = 0; nt < 8; nt++)
            Op[(size_t)row * HH + nt * 16 + lr] = (bfloat)(o[nt][j] * inv);
    }
}

// ---------------- launch ----------------
extern "C" void kernel_launch(void* const* d_in, const int* in_sizes, int n_in,
                              void* d_out, int out_size, void* d_ws, size_t ws_size,
                              hipStream_t stream) {
    (void)in_sizes; (void)n_in; (void)out_size; (void)ws_size;
    const float* hs = (const float*)d_in[0];
    const float* Wq = (const float*)d_in[2];
    const float* bq = (const float*)d_in[3];
    const float* Wk = (const float*)d_in[4];
    const float* bk = (const float*)d_in[5];
    const float* Wv = (const float*)d_in[6];
    const float* bv = (const float*)d_in[7];
    const float* Wo = (const float*)d_in[8];
    const float* bo = (const float*)d_in[9];

    char* ws = (char*)d_ws;
    size_t off = 0;
    auto alloc = [&](size_t bytes) { void* p = ws + off; off += (bytes + 255) & ~(size_t)255; return p; };
    const size_t MK = (size_t)BB * SS * HH;   // 8M elems
    const size_t NK = (size_t)HH * HH;        // 4M elems

    bfloat* Xb  = (bfloat*)alloc(MK * 2);
    bfloat* Wqb = (bfloat*)alloc(NK * 2);
    bfloat* Wkb = (bfloat*)alloc(NK * 2);
    bfloat* Wvb = (bfloat*)alloc(NK * 2);
    bfloat* Wob = (bfloat*)alloc(NK * 2);
    bfloat* Qb  = (bfloat*)alloc(MK * 2);
    bfloat* Kb  = (bfloat*)alloc(MK * 2);
    bfloat* Vtb = (bfloat*)alloc(MK * 2);     // (b, h, d, s)
    float*  cosT = (float*)alloc((size_t)SS * 64 * 4);
    float*  sinT = (float*)alloc((size_t)SS * 64 * 4);
    bfloat* AOb = Xb;   // reuse: X no longer needed after QKV GEMM

    cvt_bf16<<<(int)(MK / 4 / 256), 256, 0, stream>>>(hs, Xb, (int)(MK / 4));
    cvt_bf16_w<<<4 * 4096, 256, 0, stream>>>(Wq, Wk, Wv, Wo, Wqb, Wkb, Wvb, Wob);
    rope_table<<<(SS * 64 + 255) / 256, 256, 0, stream>>>(cosT, sinT);

    gemm_qkv<<<dim3(BB * SS / 128, 48), 256, 0, stream>>>(
        Xb, Wqb, Wkb, Wvb, bq, bk, bv, Qb, Kb, Vtb, cosT, sinT);

    attn_fwd<<<1024, 256, 0, stream>>>(Qb, Kb, Vtb, AOb);

    gemm_out<<<dim3(BB * SS / 128, HH / 128), 256, 0, stream>>>(
        AOb, Wob, bo, (float*)d_out, BB * SS, HH, HH);
}